// Round 5
// baseline (321.340 us; speedup 1.0000x reference)
//
#include <hip/hip_runtime.h>
#include <math.h>

// Problem constants (fixed by setup_inputs)
#define BB 32
#define NN 1024
#define DD 1024
#define HH 512

// out layout (floats): [one_hot 32*1024*1024][masked_acts 32*1024][kl 32][log_nom 32][log_norm 32]
#define OUT0_OFF 0
#define OUT1_OFF (BB * NN * NN)
#define OUT2_OFF (OUT1_OFF + BB * NN)
#define OUT3_OFF (OUT2_OFF + BB)
#define OUT4_OFF (OUT3_OFF + BB)

// ws layout (bytes): acts fp32 [32768] @0 ; W1T bf16 [512][1024] @131072 ; rank int[32768] @1179648
#define WS_ACTS 0
#define WS_W1T  131072
#define WS_RANK 1179648

typedef __attribute__((ext_vector_type(8))) short short8;
typedef __attribute__((ext_vector_type(4))) float floatx4;

__device__ inline unsigned int f2bf(float x) {  // RNE fp32 -> bf16 bits
    unsigned int u = __builtin_bit_cast(unsigned int, x);
    return (u + 0x7FFFu + ((u >> 16) & 1u)) >> 16;
}

// async global->LDS DMA, 16 B per lane, LDS dest = wave-uniform base + lane*16
__device__ inline void gload_lds16(const void* g, void* l) {
    __builtin_amdgcn_global_load_lds(
        (const __attribute__((address_space(1))) unsigned int*)g,
        (__attribute__((address_space(3))) unsigned int*)l, 16, 0, 0);
}

// ---------------------------------------------------------------------------
// K0: transpose + convert W1 [d=1024][h=512] fp32 -> W1T [h=512][d=1024] bf16
// ---------------------------------------------------------------------------
__global__ __launch_bounds__(1024) void w1t_kernel(const float* __restrict__ W1,
                                                   unsigned short* __restrict__ W1T)
{
    __shared__ float T[32][33];
    const int tx = threadIdx.x, ty = threadIdx.y;
    const int d0 = blockIdx.x * 32, h0 = blockIdx.y * 32;
    T[ty][tx] = W1[(d0 + ty) * HH + h0 + tx];
    __syncthreads();
    W1T[(size_t)(h0 + ty) * DD + d0 + tx] = (unsigned short)f2bf(T[tx][ty]);
}

// ---------------------------------------------------------------------------
// K1: MFMA GEMM + fused relu/W2 epilogue.
// ROUND-5 GEOMETRY: 512 threads (8 waves), MT=64, N=512, K-step 32,
// grid 512 = 2 blocks/CU.  Wave w owns cols w*64..+64 (tn 0..3), ALL 64 rows
// (tm 0..3) -> acc[4][4] = 64 AGPR -> total regs ~120 <= 128 ->
// 4 WAVES/SIMD (16 waves/CU), double every previous round's TLP.
// (Rounds 0-4 all ran 2 waves/SIMD: acc[8][4]=128 AGPR + ~112 VGPR = 240 regs
// capped occupancy; every schedule variant converged to ~84 us because the
// SIMDs had nothing to swap in during the barrier+L2 chain.)
// Per K-step (counted-vmcnt, T4 issue-before-wait, static buffer parity):
//   { lgkmcnt(0); s_barrier;
//     issue 4 B-DMA(k+1) -> Bs[nxt]; s_waitcnt vmcnt(4)  // prev iter's 5
//     pack A(k+1) -> As[nxt]; issue A-load(k+2);          // retired, new 4 fly
//     ds_read + 16 MFMA on tile k }
// B staging: zero-VGPR global_load_lds; A staging: 1 float4/thread, depth 2.
// LDS rows 64 B, XOR swizzle byte[5:4] ^= ((row>>1)&3) on BOTH DMA source and
// frag reads (rule 21) -> measured 0 bank conflicts.
// LDS: 2*32K B + 2*4K A + 2K red = 74 KB -> 2 blocks/CU.
// Tripwire: if VGPR>128 the allocator spills (WRITE_SIZE balloons) -> revert.
// ---------------------------------------------------------------------------
#define MT 64

#define GEMM_STAGE(kk, NXTBUF)                                                 \
    do {                                                                       \
        if ((kk) < 31) {                                                       \
            _Pragma("unroll")                                                  \
            for (int j = 0; j < 4; ++j)                                        \
                gload_lds16(w1tb + (boff[j] + ((kk) + 1) * 64),                \
                            (char*)(&Bs[NXTBUF][0]) + (w * 4 + j) * 1024);     \
            asm volatile("s_waitcnt vmcnt(4)" ::: "memory");                   \
            uint2 pk;                                                          \
            pk.x = f2bf(a0.x) | (f2bf(a0.y) << 16);                            \
            pk.y = f2bf(a0.z) | (f2bf(a0.w) << 16);                            \
            *(uint2*)((char*)(&As[NXTBUF][0]) + srow * 64 + asw) = pk;         \
            const int ka = ((kk) < 30) ? (kk) + 2 : 31;                        \
            a0 = *(const float4*)(aptr + ka * 32);                             \
        } else {                                                               \
            asm volatile("s_waitcnt vmcnt(0)" ::: "memory");                   \
        }                                                                      \
    } while (0)

#define GEMM_COMPUTE(CURBUF)                                                   \
    do {                                                                       \
        __builtin_amdgcn_s_setprio(1);                                         \
        short8 af[4];                                                          \
        _Pragma("unroll")                                                      \
        for (int tm = 0; tm < 4; ++tm)                                         \
            af[tm] = *(const short8*)((const char*)(&As[CURBUF][0]) + aoff[tm]);\
        _Pragma("unroll")                                                      \
        for (int tn = 0; tn < 4; ++tn) {                                       \
            short8 bf =                                                        \
                *(const short8*)((const char*)(&Bs[CURBUF][0]) + boffr[tn]);   \
            _Pragma("unroll")                                                  \
            for (int tm = 0; tm < 4; ++tm)                                     \
                acc[tn][tm] = __builtin_amdgcn_mfma_f32_16x16x32_bf16(         \
                    af[tm], bf, acc[tn][tm], 0, 0, 0);                         \
        }                                                                      \
        __builtin_amdgcn_s_setprio(0);                                         \
    } while (0)

#define GEMM_BODY(kk, CURBUF)                                                  \
    do {                                                                       \
        asm volatile("s_waitcnt lgkmcnt(0)" ::: "memory");                     \
        __builtin_amdgcn_s_barrier();                                          \
        GEMM_STAGE(kk, (CURBUF) ^ 1);                                          \
        GEMM_COMPUTE(CURBUF);                                                  \
    } while (0)

__global__ __launch_bounds__(512, 4) void gemm_acts_kernel(
    const float* __restrict__ q, const unsigned short* __restrict__ W1T,
    const float* __restrict__ b1, const float* __restrict__ W2,
    const float* __restrict__ b2, const float* __restrict__ unoise,
    float* __restrict__ acts_ws, float* __restrict__ out1)
{
    __shared__ short As[2][MT * 32];   // 2 x 4096 B, swizzled 64 B rows
    __shared__ short Bs[2][HH * 32];   // 2 x 32768 B, swizzled 64 B rows
    __shared__ float red[MT][8];

    const int tid  = threadIdx.x;
    const int w    = tid >> 6;         // wave 0..7
    const int lane = tid & 63;
    const int c    = lane & 15;        // fragment row/col-in-tile
    const int qd   = lane >> 4;        // quad 0..3
    const int m0   = blockIdx.x * MT;

    floatx4 acc[4][4];
    #pragma unroll
    for (int tn = 0; tn < 4; ++tn)
        #pragma unroll
        for (int tm = 0; tm < 4; ++tm)
            acc[tn][tm] = (floatx4){0.f, 0.f, 0.f, 0.f};

    // B DMA: 32 chunks of 1 KB (16 rows x 64 B); wave w stages chunks w*4+j.
    // Lane covers row n = chunk*16 + (lane>>2), stored col c0 = (lane&3)*16.
    // Stored col c0 holds element bytes c0 ^ (s<<4), s = (n>>1)&3 (involution),
    // so pre-swizzle the SOURCE address (m173 pattern).
    int boff[4];
    #pragma unroll
    for (int j = 0; j < 4; ++j) {
        int n  = (w * 4 + j) * 16 + (lane >> 2);
        int c0 = (lane & 3) * 16;
        int s  = (n >> 1) & 3;
        boff[j] = n * 2048 + (c0 ^ (s << 4));
    }
    const char* w1tb = (const char*)W1T;

    // A staging: thread -> row srow=tid/8 (0..63), 4 floats at (tid%8)*4;
    // packs to an 8-byte group at byte (tid%8)*8 of the 64-B row.  The XOR
    // swizzle moves 16-B units, so the 8-B group keeps its low 8-bit offset:
    //   aswz = ((b & 0x30) ^ (s<<4)) | (b & 8),  b = (tid%8)*8, s=(srow>>1)&3
    const int srow = tid >> 3;
    const int sk4  = (tid & 7) * 4;
    const float* aptr = q + (size_t)(m0 + srow) * DD + sk4;
    const int ab  = (tid & 7) * 8;
    const int asw = ((ab & 0x30) ^ (((srow >> 1) & 3) << 4)) | (ab & 8);

    // loop-invariant frag-read byte offsets (same XOR on the read side)
    int aoff[4], boffr[4];
    #pragma unroll
    for (int tm = 0; tm < 4; ++tm) {
        int r = tm * 16 + c;
        aoff[tm] = r * 64 + ((qd * 16) ^ (((r >> 1) & 3) << 4));
    }
    #pragma unroll
    for (int tn = 0; tn < 4; ++tn) {
        int n = w * 64 + tn * 16 + c;
        boffr[tn] = n * 64 + ((qd * 16) ^ (((n >> 1) & 3) << 4));
    }

    float4 a0;

    // ---- prologue: issue B DMA(0) -> Bs[0]; pack A(0) -> As[0] (sync);
    //      issue A-load(1).  vm outstanding entering loop = 5 per wave. ----
    #pragma unroll
    for (int j = 0; j < 4; ++j)
        gload_lds16(w1tb + boff[j], (char*)(&Bs[0][0]) + (w * 4 + j) * 1024);
    {
        float4 v0 = *(const float4*)aptr;
        uint2 pk;
        pk.x = f2bf(v0.x) | (f2bf(v0.y) << 16);
        pk.y = f2bf(v0.z) | (f2bf(v0.w) << 16);
        *(uint2*)((char*)(&As[0][0]) + srow * 64 + asw) = pk;
        a0 = *(const float4*)(aptr + 32);
    }

    #pragma unroll 1
    for (int ku = 0; ku < 16; ++ku) {
        GEMM_BODY(ku * 2,     0);
        GEMM_BODY(ku * 2 + 1, 1);
    }

    // epilogue: h = relu(acc + b1); rowsum += h*W2; reduce 16 cols + 8 waves
    float b1v[4], w2v[4];
    #pragma unroll
    for (int tn = 0; tn < 4; ++tn) {
        int col = w * 64 + tn * 16 + c;
        b1v[tn] = b1[col];
        w2v[tn] = W2[col];
    }
    #pragma unroll
    for (int tm = 0; tm < 4; ++tm) {
        #pragma unroll
        for (int r = 0; r < 4; ++r) {
            float p = 0.f;
            #pragma unroll
            for (int tn = 0; tn < 4; ++tn) {
                float v = acc[tn][tm][r] + b1v[tn];
                p = fmaf(fmaxf(v, 0.f), w2v[tn], p);
            }
            p += __shfl_xor(p, 1);
            p += __shfl_xor(p, 2);
            p += __shfl_xor(p, 4);
            p += __shfl_xor(p, 8);
            if (c == 0) red[tm * 16 + qd * 4 + r][w] = p;
        }
    }
    __syncthreads();
    if (tid < MT) {
        float raw = red[tid][0] + red[tid][1] + red[tid][2] + red[tid][3] +
                    red[tid][4] + red[tid][5] + red[tid][6] + red[tid][7] + b2[0];
        float sp = fmaxf(raw, 0.f) + log1pf(expf(-fabsf(raw)));  // stable softplus
        int row = m0 + tid;
        float av = logf(fmaxf(sp, 1e-5f)) + unoise[row];
        acts_ws[row] = av;
        out1[row]    = av;
    }
}

// ---------------------------------------------------------------------------
// K2: zero the one-hot output region
// ---------------------------------------------------------------------------
__global__ __launch_bounds__(256) void zero_kernel(float4* __restrict__ p, int n4)
{
    int idx = blockIdx.x * blockDim.x + threadIdx.x;
    int stride = gridDim.x * blockDim.x;
    float4 z = make_float4(0.f, 0.f, 0.f, 0.f);
    for (int i = idx; i < n4; i += stride) p[i] = z;
}

// ---------------------------------------------------------------------------
// K3: rank-by-counting, spread across 128 blocks (4 per batch, 256 i each)
// ---------------------------------------------------------------------------
__global__ __launch_bounds__(256) void rank_kernel(
    const float* __restrict__ acts_ws, const float* __restrict__ gumbel,
    int* __restrict__ rank)
{
    __shared__ float P[NN];
    const int b = blockIdx.x >> 2;
    const int chunk = blockIdx.x & 3;
    const int tid = threadIdx.x;
    #pragma unroll
    for (int r = 0; r < 4; ++r) {
        int j = r * 256 + tid;
        P[j] = acts_ws[b * NN + j] + gumbel[b * NN + j];
    }
    __syncthreads();
    const int i = chunk * 256 + tid;
    const float pert = P[i];
    int cnt = 0;
    const float4* P4 = (const float4*)P;
    for (int j4 = 0; j4 < NN / 4; ++j4) {
        float4 pv = P4[j4];  // broadcast
        int j = j4 * 4;
        cnt += (pv.x > pert) || (pv.x == pert && j + 0 < i);
        cnt += (pv.y > pert) || (pv.y == pert && j + 1 < i);
        cnt += (pv.z > pert) || (pv.z == pert && j + 2 < i);
        cnt += (pv.w > pert) || (pv.w == pert && j + 3 < i);
    }
    rank[b * NN + i] = cnt;
}

// ---------------------------------------------------------------------------
// K4: per-batch permutation, one-hot scatter, PL likelihood, kl.
// Wave-level shfl suffix-scan + butterfly reductions: 4 block barriers total.
// ---------------------------------------------------------------------------
__global__ __launch_bounds__(1024) void permu_stats_kernel(
    const float* __restrict__ acts_ws, const int* __restrict__ rank,
    float* __restrict__ out0, float* __restrict__ out2,
    float* __restrict__ out3, float* __restrict__ out4)
{
    __shared__ float A[NN];
    __shared__ int   IDX[NN];
    __shared__ float WT[16];
    __shared__ float WSUF[17];
    __shared__ float P0[16], P1[16], P2[16];

    const int b = blockIdx.x;
    const int i = threadIdx.x;
    const int lane = i & 63;
    const int w = i >> 6;            // wave 0..15

    float a = acts_ws[b * NN + i];
    A[i] = a;
    IDX[rank[b * NN + i]] = i;
    __syncthreads();                                        // barrier A

    int perm = (i == 0) ? 0 : IDX[i - 1];
    out0[((size_t)b * NN + i) * NN + perm] = 1.0f;

    float e = expf(A[perm]);
    // intra-wave inclusive suffix sum of e
    float s = e;
    #pragma unroll
    for (int off = 1; off < 64; off <<= 1) {
        float v = __shfl_down(s, off);
        if (lane + off < 64) s += v;
    }
    if (lane == 0) WT[w] = s;        // wave total (suffix from lane 0)
    __syncthreads();                                        // barrier B
    if (w == 0) {
        float t = (lane < 16) ? WT[lane] : 0.f;
        #pragma unroll
        for (int off = 1; off < 16; off <<= 1) {
            float v = __shfl_down(t, off);
            if (lane + off < 16) t += v;
        }
        if (lane < 16) WSUF[lane] = t;   // sum over waves >= lane
        if (lane == 0) WSUF[16] = 0.f;
    }
    __syncthreads();                                        // barrier C

    float S = s + WSUF[w + 1];       // full suffix sum_{j>=i} e_j
    float term = logf(e + 1e-20f) - logf(S + 1e-20f);

    // three simultaneous full-wave butterfly reductions
    float r0 = term, r1 = a, r2 = expf(-fmaxf(a, -20.f));
    #pragma unroll
    for (int off = 1; off < 64; off <<= 1) {
        r0 += __shfl_xor(r0, off);
        r1 += __shfl_xor(r1, off);
        r2 += __shfl_xor(r2, off);
    }
    if (lane == 0) { P0[w] = r0; P1[w] = r1; P2[w] = r2; }
    __syncthreads();                                        // barrier D
    if (i == 0) {
        float t0 = 0.f, t1 = 0.f, t2 = 0.f;
        #pragma unroll
        for (int k = 0; k < 16; ++k) { t0 += P0[k]; t1 += P1[k]; t2 += P2[k]; }
        out3[b] = t0;
        out2[b] = -(float)NN + t1 + t2;
        out4[b] = 0.f;
    }
}

extern "C" void kernel_launch(void* const* d_in, const int* in_sizes, int n_in,
                              void* d_out, int out_size, void* d_ws, size_t ws_size,
                              hipStream_t stream)
{
    const float* q      = (const float*)d_in[0];
    const float* W1     = (const float*)d_in[2];
    const float* b1     = (const float*)d_in[3];
    const float* W2     = (const float*)d_in[4];
    const float* b2     = (const float*)d_in[5];
    const float* unoise = (const float*)d_in[6];
    const float* gumbel = (const float*)d_in[7];

    float* out  = (float*)d_out;
    char*  ws   = (char*)d_ws;
    float*          acts = (float*)(ws + WS_ACTS);
    unsigned short* W1T  = (unsigned short*)(ws + WS_W1T);
    int*            rank = (int*)(ws + WS_RANK);

    w1t_kernel<<<dim3(32, 16), dim3(32, 32), 0, stream>>>(W1, W1T);
    gemm_acts_kernel<<<(BB * NN) / MT, 512, 0, stream>>>(q, W1T, b1, W2, b2,
                                                         unoise, acts,
                                                         out + OUT1_OFF);
    zero_kernel<<<8192, 256, 0, stream>>>((float4*)(out + OUT0_OFF),
                                          (BB * NN * NN) / 4);
    rank_kernel<<<BB * 4, 256, 0, stream>>>(acts, gumbel, rank);
    permu_stats_kernel<<<BB, 1024, 0, stream>>>(acts, rank,
                                                out + OUT0_OFF, out + OUT2_OFF,
                                                out + OUT3_OFF, out + OUT4_OFF);
}

// Round 6
// 320.360 us; speedup vs baseline: 1.0031x; 1.0031x over previous
//
#include <hip/hip_runtime.h>
#include <math.h>

// Problem constants (fixed by setup_inputs)
#define BB 32
#define NN 1024
#define DD 1024
#define HH 512

// out layout (floats): [one_hot 32*1024*1024][masked_acts 32*1024][kl 32][log_nom 32][log_norm 32]
#define OUT0_OFF 0
#define OUT1_OFF (BB * NN * NN)
#define OUT2_OFF (OUT1_OFF + BB * NN)
#define OUT3_OFF (OUT2_OFF + BB)
#define OUT4_OFF (OUT3_OFF + BB)

// ws layout (bytes): acts fp32 [32768] @0 ; W1T bf16 [512][1024] @131072 ; rank int[32768] @1179648
#define WS_ACTS 0
#define WS_W1T  131072
#define WS_RANK 1179648

typedef __attribute__((ext_vector_type(8))) short short8;
typedef __attribute__((ext_vector_type(4))) float floatx4;

__device__ inline unsigned int f2bf(float x) {  // RNE fp32 -> bf16 bits
    unsigned int u = __builtin_bit_cast(unsigned int, x);
    return (u + 0x7FFFu + ((u >> 16) & 1u)) >> 16;
}

// async global->LDS DMA, 16 B per lane, LDS dest = wave-uniform base + lane*16
__device__ inline void gload_lds16(const void* g, void* l) {
    __builtin_amdgcn_global_load_lds(
        (const __attribute__((address_space(1))) unsigned int*)g,
        (__attribute__((address_space(3))) unsigned int*)l, 16, 0, 0);
}

// ---------------------------------------------------------------------------
// K0: transpose + convert W1 [d=1024][h=512] fp32 -> W1T [h=512][d=1024] bf16
// ---------------------------------------------------------------------------
__global__ __launch_bounds__(1024) void w1t_kernel(const float* __restrict__ W1,
                                                   unsigned short* __restrict__ W1T)
{
    __shared__ float T[32][33];
    const int tx = threadIdx.x, ty = threadIdx.y;
    const int d0 = blockIdx.x * 32, h0 = blockIdx.y * 32;
    T[ty][tx] = W1[(d0 + ty) * HH + h0 + tx];
    __syncthreads();
    W1T[(size_t)(h0 + ty) * DD + d0 + tx] = (unsigned short)f2bf(T[tx][ty]);
}

// ---------------------------------------------------------------------------
// K1: MFMA GEMM + fused relu/W2 epilogue.  ROUND-6: BK=64 per barrier period.
// All rounds 0-5 converged to 84-89 us at one barrier per 32-K step (m233's
// 2-phase pathology: stage+vmcnt+barrier ~= 72% of each period).  Key insight:
// B staging is WAVE-PRIVATE (wave w DMAs exactly the cols w*64..+64 it alone
// consumes) -> B needs NO barrier, only per-wave counted vmcnt.  Only the
// cooperative A-tile needs block sync -> barrier per BK=64 (16 total, 32
// MFMA/wave/period).  Per period (steady state; in-order vmcnt retirement):
//   entering outstanding (oldest->newest): [DMA_a(4)=sub0, Aload(2), DMA_b(4)=sub1]
//   lgkmcnt(0); barrier                 // A(s) pack visible
//   vmcnt(6)   -> DMA_a retired, sub0 in Bs[0]
//   R0 (8 ds_read) ; 16 MFMA ; SB ; issue DMA_c(4)=next sub0 ; SB
//   vmcnt(4)   -> Aload+DMA_b retired: A-regs ready, sub1 in Bs[1]
//   R1 ; pack A(s+1)->As[p^1] ; issue Aload(s+2) ; SB ; 16 MFMA ; SB
//   issue DMA_d(4)=next sub1 ; SB      // leaves [DMA_c, Aload, DMA_d] in flight
// DMAs issue only AFTER the MFMA cluster that consumed the target buffer
// (reads lgkm-drained before first MFMA) -> no stale-read hazard.
// sched_barrier(0) pins issue-group order (plain Aload would otherwise hoist
// across the DMA builtins and corrupt the vmcnt ledger).
// A rows 128 B: XOR swizzle byte ^= ((row&7)<<4), write side via pre-XOR'd
// source group (grp^(row&7)), read side same XOR -> 8-slot spread, ~2-way.
// B layout/swizzle identical to round 5 (measured ~0 conflicts).
// LDS: 2*32K B + 2*8K A = 80 KB exactly (red aliases dead As in epilogue)
// -> 2 blocks/CU; acc[4][4]=64 AGPR, ~115 regs -> 4 waves/SIMD.
// ---------------------------------------------------------------------------
#define MT 64
#define SB() __builtin_amdgcn_sched_barrier(0)

__global__ __launch_bounds__(512, 4) void gemm_acts_kernel(
    const float* __restrict__ q, const unsigned short* __restrict__ W1T,
    const float* __restrict__ b1, const float* __restrict__ W2,
    const float* __restrict__ b2, const float* __restrict__ unoise,
    float* __restrict__ acts_ws, float* __restrict__ out1)
{
    __shared__ short As[2][MT * 64];   // 2 x 8192 B  (64 rows x 128 B, swizzled)
    __shared__ short Bs[2][HH * 32];   // 2 x 32768 B (512 rows x 64 B, swizzled)

    const int tid  = threadIdx.x;
    const int w    = tid >> 6;         // wave 0..7
    const int lane = tid & 63;
    const int c    = lane & 15;        // fragment row/col-in-tile
    const int qd   = lane >> 4;        // quad 0..3
    const int m0   = blockIdx.x * MT;

    floatx4 acc[4][4];
    #pragma unroll
    for (int tn = 0; tn < 4; ++tn)
        #pragma unroll
        for (int tm = 0; tm < 4; ++tm)
            acc[tn][tm] = (floatx4){0.f, 0.f, 0.f, 0.f};

    // B DMA: wave w stages its own 4 chunks (rows w*64..+63), 16 rows x 64 B
    // each.  Lane -> row n = chunk*16 + (lane>>2), stored col (lane&3)*16,
    // source pre-XOR'd by ((n>>1)&3)<<4 (same involution as the frag read).
    int boff[4];
    #pragma unroll
    for (int j = 0; j < 4; ++j) {
        int n  = (w * 4 + j) * 16 + (lane >> 2);
        int c0 = (lane & 3) * 16;
        int s  = (n >> 1) & 3;
        boff[j] = n * 2048 + (c0 ^ (s << 4));   // + jg*64 selects K sub-chunk
    }
    const char* w1tb = (const char*)W1T;

    // A staging: thread -> row arow = tid>>3 (0..63), group agrp = tid&7.
    // Stored byte b of a row holds element byte b ^ ((arow&7)<<4), so the
    // thread at dst slot agrp loads source float group agrp^(arow&7).
    const int arow = tid >> 3;
    const int agrp = tid & 7;
    const float* aptrA = q + (size_t)(m0 + arow) * DD + ((agrp ^ (arow & 7)) * 8);
    const int adst = arow * 128 + agrp * 16;   // linear dst byte (swizzle via src)

    // frag-read byte offsets (A: sub0 slot qd^(r&7), sub1 slot (4+qd)^(r&7))
    int aoffA[4], aoffB[4], boffr[4];
    #pragma unroll
    for (int tm = 0; tm < 4; ++tm) {
        int r = tm * 16 + c;
        aoffA[tm] = r * 128 + 16 * ((qd)     ^ (r & 7));
        aoffB[tm] = r * 128 + 16 * ((4 + qd) ^ (r & 7));
    }
    #pragma unroll
    for (int tn = 0; tn < 4; ++tn) {
        int n = w * 64 + tn * 16 + c;
        boffr[tn] = n * 64 + ((qd * 16) ^ (((n >> 1) & 3) << 4));
    }

    float4 a0, a1;

    // ---- prologue ----
    {   // pack A(s=0) -> As[0] (sync: pack's use of v0/v1 drains these loads
        // before the ledger-critical issues below)
        float4 v0 = *(const float4*)(aptrA + 0);
        float4 v1 = *(const float4*)(aptrA + 4);
        uint4 pk;
        pk.x = f2bf(v0.x) | (f2bf(v0.y) << 16);
        pk.y = f2bf(v0.z) | (f2bf(v0.w) << 16);
        pk.z = f2bf(v1.x) | (f2bf(v1.y) << 16);
        pk.w = f2bf(v1.z) | (f2bf(v1.w) << 16);
        *(uint4*)((char*)(&As[0][0]) + adst) = pk;
    }
    SB();
    #pragma unroll
    for (int j = 0; j < 4; ++j)                         // DMA_a: sub jg=0
        gload_lds16(w1tb + boff[j], (char*)(&Bs[0][0]) + (w * 4 + j) * 1024);
    SB();
    a0 = *(const float4*)(aptrA + 64);                  // Aload(s=1)
    a1 = *(const float4*)(aptrA + 64 + 4);
    SB();
    #pragma unroll
    for (int j = 0; j < 4; ++j)                         // DMA_b: sub jg=1
        gload_lds16(w1tb + (boff[j] + 64), (char*)(&Bs[1][0]) + (w * 4 + j) * 1024);
    SB();
    // outstanding: [DMA_a(4), Aload(2), DMA_b(4)]  -- steady-state pattern

    #pragma unroll 1
    for (int s = 0; s < 16; ++s) {
        const int p = s & 1;
        const char* asP = (const char*)(&As[p][0]);
        char*       asN = (char*)(&As[p ^ 1][0]);

        asm volatile("s_waitcnt lgkmcnt(0)" ::: "memory");
        __builtin_amdgcn_s_barrier();                   // A(s) visible
        asm volatile("s_waitcnt vmcnt(6)" ::: "memory");  // sub0 landed

        // ---- sub-step 0: K range [64s, 64s+32) from Bs[0] ----
        {
            short8 af[4];
            #pragma unroll
            for (int tm = 0; tm < 4; ++tm)
                af[tm] = *(const short8*)(asP + aoffA[tm]);
            __builtin_amdgcn_s_setprio(1);
            #pragma unroll
            for (int tn = 0; tn < 4; ++tn) {
                short8 bf = *(const short8*)((const char*)(&Bs[0][0]) + boffr[tn]);
                #pragma unroll
                for (int tm = 0; tm < 4; ++tm)
                    acc[tn][tm] = __builtin_amdgcn_mfma_f32_16x16x32_bf16(
                        af[tm], bf, acc[tn][tm], 0, 0, 0);
            }
            __builtin_amdgcn_s_setprio(0);
        }
        SB();
        if (s < 15) {   // DMA_c: next sub0 -> Bs[0] (its readers are drained)
            #pragma unroll
            for (int j = 0; j < 4; ++j)
                gload_lds16(w1tb + (boff[j] + (2 * s + 2) * 64),
                            (char*)(&Bs[0][0]) + (w * 4 + j) * 1024);
            SB();
            asm volatile("s_waitcnt vmcnt(4)" ::: "memory"); // Aload+sub1 landed
        } else {
            asm volatile("s_waitcnt vmcnt(0)" ::: "memory");
        }

        // ---- sub-step 1: K range [64s+32, 64s+64) from Bs[1] ----
        {
            short8 af[4];
            #pragma unroll
            for (int tm = 0; tm < 4; ++tm)
                af[tm] = *(const short8*)(asP + aoffB[tm]);
            if (s < 15) {   // pack A(s+1) and issue Aload(s+2)
                uint4 pk;
                pk.x = f2bf(a0.x) | (f2bf(a0.y) << 16);
                pk.y = f2bf(a0.z) | (f2bf(a0.w) << 16);
                pk.z = f2bf(a1.x) | (f2bf(a1.y) << 16);
                pk.w = f2bf(a1.z) | (f2bf(a1.w) << 16);
                *(uint4*)(asN + adst) = pk;
                SB();
                const int ka = (s < 14) ? s + 2 : 15;   // clamped dummy at s=14
                a0 = *(const float4*)(aptrA + ka * 64);
                a1 = *(const float4*)(aptrA + ka * 64 + 4);
                SB();
            }
            __builtin_amdgcn_s_setprio(1);
            #pragma unroll
            for (int tn = 0; tn < 4; ++tn) {
                short8 bf = *(const short8*)((const char*)(&Bs[1][0]) + boffr[tn]);
                #pragma unroll
                for (int tm = 0; tm < 4; ++tm)
                    acc[tn][tm] = __builtin_amdgcn_mfma_f32_16x16x32_bf16(
                        af[tm], bf, acc[tn][tm], 0, 0, 0);
            }
            __builtin_amdgcn_s_setprio(0);
        }
        SB();
        if (s < 15) {   // DMA_d: next sub1 -> Bs[1]
            #pragma unroll
            for (int j = 0; j < 4; ++j)
                gload_lds16(w1tb + (boff[j] + (2 * s + 3) * 64),
                            (char*)(&Bs[1][0]) + (w * 4 + j) * 1024);
            SB();
        }
        // leaves [DMA_c(4), Aload(2), DMA_d(4)] in flight across the barrier
    }

    // epilogue: h = relu(acc + b1); rowsum += h*W2; reduce 16 cols + 8 waves.
    // red aliases the (now dead) A buffers: 64*8*4 B = 2 KB << 16 KB.
    float (*red)[8] = (float (*)[8])(&As[0][0]);
    float b1v[4], w2v[4];
    #pragma unroll
    for (int tn = 0; tn < 4; ++tn) {
        int col = w * 64 + tn * 16 + c;
        b1v[tn] = b1[col];
        w2v[tn] = W2[col];
    }
    __syncthreads();   // all waves done with As/Bs reads before red reuse
    #pragma unroll
    for (int tm = 0; tm < 4; ++tm) {
        #pragma unroll
        for (int r = 0; r < 4; ++r) {
            float p = 0.f;
            #pragma unroll
            for (int tn = 0; tn < 4; ++tn) {
                float v = acc[tn][tm][r] + b1v[tn];
                p = fmaf(fmaxf(v, 0.f), w2v[tn], p);
            }
            p += __shfl_xor(p, 1);
            p += __shfl_xor(p, 2);
            p += __shfl_xor(p, 4);
            p += __shfl_xor(p, 8);
            if (c == 0) red[tm * 16 + qd * 4 + r][w] = p;
        }
    }
    __syncthreads();
    if (tid < MT) {
        float raw = red[tid][0] + red[tid][1] + red[tid][2] + red[tid][3] +
                    red[tid][4] + red[tid][5] + red[tid][6] + red[tid][7] + b2[0];
        float sp = fmaxf(raw, 0.f) + log1pf(expf(-fabsf(raw)));  // stable softplus
        int row = m0 + tid;
        float av = logf(fmaxf(sp, 1e-5f)) + unoise[row];
        acts_ws[row] = av;
        out1[row]    = av;
    }
}

// ---------------------------------------------------------------------------
// K2: zero the one-hot output region
// ---------------------------------------------------------------------------
__global__ __launch_bounds__(256) void zero_kernel(float4* __restrict__ p, int n4)
{
    int idx = blockIdx.x * blockDim.x + threadIdx.x;
    int stride = gridDim.x * blockDim.x;
    float4 z = make_float4(0.f, 0.f, 0.f, 0.f);
    for (int i = idx; i < n4; i += stride) p[i] = z;
}

// ---------------------------------------------------------------------------
// K3: rank-by-counting, spread across 128 blocks (4 per batch, 256 i each)
// ---------------------------------------------------------------------------
__global__ __launch_bounds__(256) void rank_kernel(
    const float* __restrict__ acts_ws, const float* __restrict__ gumbel,
    int* __restrict__ rank)
{
    __shared__ float P[NN];
    const int b = blockIdx.x >> 2;
    const int chunk = blockIdx.x & 3;
    const int tid = threadIdx.x;
    #pragma unroll
    for (int r = 0; r < 4; ++r) {
        int j = r * 256 + tid;
        P[j] = acts_ws[b * NN + j] + gumbel[b * NN + j];
    }
    __syncthreads();
    const int i = chunk * 256 + tid;
    const float pert = P[i];
    int cnt = 0;
    const float4* P4 = (const float4*)P;
    for (int j4 = 0; j4 < NN / 4; ++j4) {
        float4 pv = P4[j4];  // broadcast
        int j = j4 * 4;
        cnt += (pv.x > pert) || (pv.x == pert && j + 0 < i);
        cnt += (pv.y > pert) || (pv.y == pert && j + 1 < i);
        cnt += (pv.z > pert) || (pv.z == pert && j + 2 < i);
        cnt += (pv.w > pert) || (pv.w == pert && j + 3 < i);
    }
    rank[b * NN + i] = cnt;
}

// ---------------------------------------------------------------------------
// K4: per-batch permutation, one-hot scatter, PL likelihood, kl.
// Wave-level shfl suffix-scan + butterfly reductions: 4 block barriers total.
// ---------------------------------------------------------------------------
__global__ __launch_bounds__(1024) void permu_stats_kernel(
    const float* __restrict__ acts_ws, const int* __restrict__ rank,
    float* __restrict__ out0, float* __restrict__ out2,
    float* __restrict__ out3, float* __restrict__ out4)
{
    __shared__ float A[NN];
    __shared__ int   IDX[NN];
    __shared__ float WT[16];
    __shared__ float WSUF[17];
    __shared__ float P0[16], P1[16], P2[16];

    const int b = blockIdx.x;
    const int i = threadIdx.x;
    const int lane = i & 63;
    const int w = i >> 6;            // wave 0..15

    float a = acts_ws[b * NN + i];
    A[i] = a;
    IDX[rank[b * NN + i]] = i;
    __syncthreads();                                        // barrier A

    int perm = (i == 0) ? 0 : IDX[i - 1];
    out0[((size_t)b * NN + i) * NN + perm] = 1.0f;

    float e = expf(A[perm]);
    // intra-wave inclusive suffix sum of e
    float s = e;
    #pragma unroll
    for (int off = 1; off < 64; off <<= 1) {
        float v = __shfl_down(s, off);
        if (lane + off < 64) s += v;
    }
    if (lane == 0) WT[w] = s;        // wave total (suffix from lane 0)
    __syncthreads();                                        // barrier B
    if (w == 0) {
        float t = (lane < 16) ? WT[lane] : 0.f;
        #pragma unroll
        for (int off = 1; off < 16; off <<= 1) {
            float v = __shfl_down(t, off);
            if (lane + off < 16) t += v;
        }
        if (lane < 16) WSUF[lane] = t;   // sum over waves >= lane
        if (lane == 0) WSUF[16] = 0.f;
    }
    __syncthreads();                                        // barrier C

    float S = s + WSUF[w + 1];       // full suffix sum_{j>=i} e_j
    float term = logf(e + 1e-20f) - logf(S + 1e-20f);

    // three simultaneous full-wave butterfly reductions
    float r0 = term, r1 = a, r2 = expf(-fmaxf(a, -20.f));
    #pragma unroll
    for (int off = 1; off < 64; off <<= 1) {
        r0 += __shfl_xor(r0, off);
        r1 += __shfl_xor(r1, off);
        r2 += __shfl_xor(r2, off);
    }
    if (lane == 0) { P0[w] = r0; P1[w] = r1; P2[w] = r2; }
    __syncthreads();                                        // barrier D
    if (i == 0) {
        float t0 = 0.f, t1 = 0.f, t2 = 0.f;
        #pragma unroll
        for (int k = 0; k < 16; ++k) { t0 += P0[k]; t1 += P1[k]; t2 += P2[k]; }
        out3[b] = t0;
        out2[b] = -(float)NN + t1 + t2;
        out4[b] = 0.f;
    }
}

extern "C" void kernel_launch(void* const* d_in, const int* in_sizes, int n_in,
                              void* d_out, int out_size, void* d_ws, size_t ws_size,
                              hipStream_t stream)
{
    const float* q      = (const float*)d_in[0];
    const float* W1     = (const float*)d_in[2];
    const float* b1     = (const float*)d_in[3];
    const float* W2     = (const float*)d_in[4];
    const float* b2     = (const float*)d_in[5];
    const float* unoise = (const float*)d_in[6];
    const float* gumbel = (const float*)d_in[7];

    float* out  = (float*)d_out;
    char*  ws   = (char*)d_ws;
    float*          acts = (float*)(ws + WS_ACTS);
    unsigned short* W1T  = (unsigned short*)(ws + WS_W1T);
    int*            rank = (int*)(ws + WS_RANK);

    w1t_kernel<<<dim3(32, 16), dim3(32, 32), 0, stream>>>(W1, W1T);
    gemm_acts_kernel<<<(BB * NN) / MT, 512, 0, stream>>>(q, W1T, b1, W2, b2,
                                                         unoise, acts,
                                                         out + OUT1_OFF);
    zero_kernel<<<8192, 256, 0, stream>>>((float4*)(out + OUT0_OFF),
                                          (BB * NN * NN) / 4);
    rank_kernel<<<BB * 4, 256, 0, stream>>>(acts, gumbel, rank);
    permu_stats_kernel<<<BB, 1024, 0, stream>>>(acts, rank,
                                                out + OUT0_OFF, out + OUT2_OFF,
                                                out + OUT3_OFF, out + OUT4_OFF);
}